// Round 5
// baseline (833.621 us; speedup 1.0000x reference)
//
#include <hip/hip_runtime.h>
#include <math.h>

#define LEVELS 16
#define TBL 524288          // 2^19 entries per level
#define TMASK (TBL - 1)

// SH degree-4 block, constants computed exactly as round-1 (verified correct).
#define SH_BLOCK(sh, dx, dy, dz)                                                          \
    const float x2 = dx * dx, y2 = dy * dy, z2 = dz * dz;                                 \
    const float xy = dx * dy, xz = dx * dz, yz = dy * dz;                                 \
    const float x4 = x2 * x2, y4 = y2 * y2;                                               \
    const float c0  = (float)(0.5 * sqrt(1.0 / M_PI));                                    \
    const float c1  = (float)(0.5 * sqrt(3.0 / M_PI));                                    \
    const float sub = (float)(0.25 * sqrt(5.0 / M_PI));                                   \
    const float v1  = (float)(0.25 * sqrt(15.0 / M_PI));                                  \
    const float v2  = (float)(0.5 * sqrt(15.0 / M_PI));                                   \
    const float v3  = (float)(0.75 * sqrt(5.0 / M_PI));                                   \
    const float w1c = (float)(0.25 * sqrt(105.0 / M_PI));                                 \
    const float w2c = (float)(0.5 * sqrt(105.0 / M_PI));                                  \
    const float w3c = (float)(0.25 * sqrt(35.0 / (2.0 * M_PI)));                          \
    const float w4c = (float)(0.5 * sqrt(7.0 / (6.0 * M_PI)));                            \
    sh[0] = c0;                                                                           \
    sh[1] = -c1 * dy;                                                                     \
    sh[2] =  c1 * dz;                                                                     \
    sh[3] = -c1 * dx;                                                                     \
    sh[4] =  v2 * xy;                                                                     \
    sh[5] = -v2 * yz;                                                                     \
    sh[6] =  v3 * z2 - sub;                                                               \
    sh[7] = -v2 * xz;                                                                     \
    sh[8] =  v1 * x2 - v1 * y2;                                                           \
    sh[9]  = -w3c * dy * (3.0f * x2 - y2);                                                \
    sh[10] =  w2c * xy * dz;                                                              \
    sh[11] =  w4c * dy * (1.5f - 7.5f * z2);                                              \
    sh[12] =  1.24392110863372f * dz * (1.5f * z2 - 0.5f) - 0.497568443453487f * dz;      \
    sh[13] =  w4c * dx * (1.5f - 7.5f * z2);                                              \
    sh[14] =  w1c * dz * (x2 - y2);                                                       \
    sh[15] = -w3c * dx * (x2 - 3.0f * y2);                                                \
    sh[16] =  2.5033429417967f * xy * (x2 - y2);                                          \
    sh[17] = -1.77013076977993f * yz * (3.0f * x2 - y2);                                  \
    sh[18] =  0.126156626101008f * xy * (52.5f * z2 - 7.5f);                              \
    sh[19] =  0.267618617422916f * dy * (2.33333333333333f * dz * (1.5f - 7.5f * z2) + 4.0f * dz); \
    sh[20] =  1.48099765681286f * dz * (1.66666666666667f * dz * (1.5f * z2 - 0.5f) - 0.666666666666667f * dz) \
              - 0.952069922236839f * z2 + 0.317356640745613f;                             \
    sh[21] =  0.267618617422916f * dx * (2.33333333333333f * dz * (1.5f - 7.5f * z2) + 4.0f * dz); \
    sh[22] =  0.063078313050504f * (x2 - y2) * (52.5f * z2 - 7.5f);                       \
    sh[23] = -1.77013076977993f * xz * (x2 - 3.0f * y2);                                  \
    sh[24] = -3.75501441269506f * x2 * y2 + 0.625835735449176f * x4 + 0.625835735449176f * y4;

// ------------------------------------------------------------------
// Kernel 1: hash-grid gather, 4 threads per point (4 levels each).
// All 32 loads issued before any consume -> 4x in-flight vs R4.
// Thread i (of 4n): g = i / n (level group), idx = i % n.
// Consecutive lanes share g, consecutive idx -> coalesced plane writes.
// ------------------------------------------------------------------
__global__ __launch_bounds__(256, 4)
void ngp_encode4(const float* __restrict__ pos,
                 const float* __restrict__ tables,
                 float4* __restrict__ ws4, int n)
{
    const int i = blockIdx.x * blockDim.x + threadIdx.x;
    const int g = i / n;            // 0..3  (uniform within a block since n % 256 == 0)
    const int idx = i - g * n;
    if (g >= 4) return;

    const float px = pos[3 * idx + 0];
    const float py = pos[3 * idx + 1];
    const float pz = pos[3 * idx + 2];

    float2 e[4][8];
    float wxa[4], wya[4], wza[4];

    // ---- issue all 32 loads (4 levels x 8 corners) ----
#pragma unroll
    for (int s = 0; s < 4; ++s) {
        const int l = 4 * g + s;
        const float resf = (float)(16 << l);          // exact powers of two
        const float tx = px * resf, ty = py * resf, tz = pz * resf;
        const float fx = floorf(tx), fy = floorf(ty), fz = floorf(tz);
        wxa[s] = tx - fx; wya[s] = ty - fy; wza[s] = tz - fz;
        const unsigned ix = (unsigned)(int)fx;
        const unsigned iy = (unsigned)(int)fy;
        const unsigned iz = (unsigned)(int)fz;
        const unsigned hy0 = iy * 2654435761u, hy1 = hy0 + 2654435761u;
        const unsigned hz0 = iz * 805459861u,  hz1 = hz0 + 805459861u;
        const unsigned ix1 = ix + 1u;
        const float2* tb = (const float2*)tables + (size_t)l * TBL;
        e[s][0] = tb[(ix  ^ hy0 ^ hz0) & TMASK];
        e[s][1] = tb[(ix  ^ hy0 ^ hz1) & TMASK];
        e[s][2] = tb[(ix  ^ hy1 ^ hz0) & TMASK];
        e[s][3] = tb[(ix  ^ hy1 ^ hz1) & TMASK];
        e[s][4] = tb[(ix1 ^ hy0 ^ hz0) & TMASK];
        e[s][5] = tb[(ix1 ^ hy0 ^ hz1) & TMASK];
        e[s][6] = tb[(ix1 ^ hy1 ^ hz0) & TMASK];
        e[s][7] = tb[(ix1 ^ hy1 ^ hz1) & TMASK];
    }

    // ---- consume ----
    float f[8];
#pragma unroll
    for (int s = 0; s < 4; ++s) {
        const float wx = wxa[s], wy = wya[s], wz = wza[s];
        const float ux = 1.f - wx, uy = 1.f - wy, uz = 1.f - wz;
        const float c000 = ux * uy * uz, c001 = ux * uy * wz;
        const float c010 = ux * wy * uz, c011 = ux * wy * wz;
        const float c100 = wx * uy * uz, c101 = wx * uy * wz;
        const float c110 = wx * wy * uz, c111 = wx * wy * wz;
        float f0 = e[s][0].x * c000, f1 = e[s][0].y * c000;
        f0 = fmaf(e[s][1].x, c001, f0); f1 = fmaf(e[s][1].y, c001, f1);
        f0 = fmaf(e[s][2].x, c010, f0); f1 = fmaf(e[s][2].y, c010, f1);
        f0 = fmaf(e[s][3].x, c011, f0); f1 = fmaf(e[s][3].y, c011, f1);
        f0 = fmaf(e[s][4].x, c100, f0); f1 = fmaf(e[s][4].y, c100, f1);
        f0 = fmaf(e[s][5].x, c101, f0); f1 = fmaf(e[s][5].y, c101, f1);
        f0 = fmaf(e[s][6].x, c110, f0); f1 = fmaf(e[s][6].y, c110, f1);
        f0 = fmaf(e[s][7].x, c111, f0); f1 = fmaf(e[s][7].y, c111, f1);
        f[2 * s + 0] = f0;
        f[2 * s + 1] = f1;
    }

    // planes j = 2g, 2g+1 match MLP's enc[4j..4j+3] layout
    ws4[(size_t)(2 * g + 0) * n + idx] = make_float4(f[0], f[1], f[2], f[3]);
    ws4[(size_t)(2 * g + 1) * n + idx] = make_float4(f[4], f[5], f[6], f[7]);
}

// ------------------------------------------------------------------
// Kernel 2: SH encode + full MLP, per-thread fp32 (verbatim R4, proven)
// ------------------------------------------------------------------
__global__ __launch_bounds__(256)
void ngp_mlp_f32(const float4* __restrict__ ws4,
                 const float* __restrict__ dirp,
                 const float* __restrict__ Wd1, const float* __restrict__ bd1,
                 const float* __restrict__ Wd2, const float* __restrict__ bd2,
                 const float* __restrict__ Wc1, const float* __restrict__ bc1,
                 const float* __restrict__ Wc2, const float* __restrict__ bc2,
                 const float* __restrict__ Wc3, const float* __restrict__ bc3,
                 float* __restrict__ out, int n)
{
    const int idx = blockIdx.x * blockDim.x + threadIdx.x;
    if (idx >= n) return;

    float enc[32];
#pragma unroll
    for (int j = 0; j < 8; ++j) {
        const float4 q = ws4[(size_t)j * n + idx];
        enc[4 * j + 0] = q.x; enc[4 * j + 1] = q.y;
        enc[4 * j + 2] = q.z; enc[4 * j + 3] = q.w;
    }

    // ---- d1: y[64] = enc[32] @ Wd1 + bd1 ----
    float y[64];
#pragma unroll
    for (int j = 0; j < 64; ++j) y[j] = bd1[j];
#pragma unroll
    for (int l = 0; l < 16; ++l) {
        const float a0 = enc[2 * l + 0];
        const float a1 = enc[2 * l + 1];
        const float* w0 = Wd1 + (size_t)(2 * l) * 64;
#pragma unroll
        for (int j = 0; j < 64; ++j)
            y[j] = fmaf(a0, w0[j], fmaf(a1, w0[64 + j], y[j]));
    }

    // ---- d2: d[16] = relu(y) @ Wd2 + bd2 ----
    float d[16];
#pragma unroll
    for (int k = 0; k < 16; ++k) d[k] = bd2[k];
#pragma unroll
    for (int j = 0; j < 64; ++j) {
        const float a = fmaxf(y[j], 0.f);
#pragma unroll
        for (int k = 0; k < 16; ++k) d[k] = fmaf(a, Wd2[j * 16 + k], d[k]);
    }
    out[3 * n + idx] = fmaxf(d[15], 0.f);      // sigma

    // ---- SH degree-4 ----
    const float dx = dirp[3 * idx + 0];
    const float dy = dirp[3 * idx + 1];
    const float dz = dirp[3 * idx + 2];
    float sh[25];
    SH_BLOCK(sh, dx, dy, dz)

    // ---- c1: h1 = relu([d, sh] @ Wc1 + bc1) ----
    float h1[64];
#pragma unroll
    for (int j = 0; j < 64; ++j) h1[j] = bc1[j];
#pragma unroll
    for (int i = 0; i < 16; ++i) {
#pragma unroll
        for (int j = 0; j < 64; ++j) h1[j] = fmaf(d[i], Wc1[i * 64 + j], h1[j]);
    }
#pragma unroll
    for (int s = 0; s < 25; ++s) {
#pragma unroll
        for (int j = 0; j < 64; ++j) h1[j] = fmaf(sh[s], Wc1[(16 + s) * 64 + j], h1[j]);
    }

    // ---- c2: h2 = relu(h1 @ Wc2 + bc2) ----
    float h2[64];
#pragma unroll
    for (int j = 0; j < 64; ++j) h2[j] = bc2[j];
#pragma unroll
    for (int i = 0; i < 64; ++i) {
        const float a = fmaxf(h1[i], 0.f);
#pragma unroll
        for (int j = 0; j < 64; ++j) h2[j] = fmaf(a, Wc2[i * 64 + j], h2[j]);
    }

    // ---- c3 + sigmoid ----
    float r0 = bc3[0], r1 = bc3[1], r2 = bc3[2];
#pragma unroll
    for (int j = 0; j < 64; ++j) {
        const float a = fmaxf(h2[j], 0.f);
        r0 = fmaf(a, Wc3[j * 3 + 0], r0);
        r1 = fmaf(a, Wc3[j * 3 + 1], r1);
        r2 = fmaf(a, Wc3[j * 3 + 2], r2);
    }
    out[3 * idx + 0] = 1.f / (1.f + expf(-r0));
    out[3 * idx + 1] = 1.f / (1.f + expf(-r1));
    out[3 * idx + 2] = 1.f / (1.f + expf(-r2));
}

// ------------------------------------------------------------------
// Fallback: round-1 fused kernel (if ws too small) — proven correct
// ------------------------------------------------------------------
__global__ __launch_bounds__(256)
void nerf_fused(const float* __restrict__ pos,
                const float* __restrict__ dirp,
                const float* __restrict__ tables,
                const float* __restrict__ Wd1, const float* __restrict__ bd1,
                const float* __restrict__ Wd2, const float* __restrict__ bd2,
                const float* __restrict__ Wc1, const float* __restrict__ bc1,
                const float* __restrict__ Wc2, const float* __restrict__ bc2,
                const float* __restrict__ Wc3, const float* __restrict__ bc3,
                float* __restrict__ out, int n)
{
    const int idx = blockIdx.x * blockDim.x + threadIdx.x;
    if (idx >= n) return;
    const float px = pos[3 * idx + 0], py = pos[3 * idx + 1], pz = pos[3 * idx + 2];
    float y[64];
#pragma unroll
    for (int j = 0; j < 64; ++j) y[j] = bd1[j];
#pragma unroll
    for (int l = 0; l < LEVELS; ++l) {
        const float resf = (float)(16 << l);
        const float tx = px * resf, ty = py * resf, tz = pz * resf;
        const float fx = floorf(tx), fy = floorf(ty), fz = floorf(tz);
        const float wx = tx - fx, wy = ty - fy, wz = tz - fz;
        const unsigned ix = (unsigned)(int)fx, iy = (unsigned)(int)fy, iz = (unsigned)(int)fz;
        const unsigned hy0 = iy * 2654435761u, hy1 = hy0 + 2654435761u;
        const unsigned hz0 = iz * 805459861u,  hz1 = hz0 + 805459861u;
        const unsigned ix1 = ix + 1u;
        const float2* tb = (const float2*)tables + (size_t)l * TBL;
        const float2 e000 = tb[(ix  ^ hy0 ^ hz0) & TMASK];
        const float2 e001 = tb[(ix  ^ hy0 ^ hz1) & TMASK];
        const float2 e010 = tb[(ix  ^ hy1 ^ hz0) & TMASK];
        const float2 e011 = tb[(ix  ^ hy1 ^ hz1) & TMASK];
        const float2 e100 = tb[(ix1 ^ hy0 ^ hz0) & TMASK];
        const float2 e101 = tb[(ix1 ^ hy0 ^ hz1) & TMASK];
        const float2 e110 = tb[(ix1 ^ hy1 ^ hz0) & TMASK];
        const float2 e111 = tb[(ix1 ^ hy1 ^ hz1) & TMASK];
        const float ux = 1.f - wx, uy = 1.f - wy, uz = 1.f - wz;
        const float c000 = ux*uy*uz, c001 = ux*uy*wz, c010 = ux*wy*uz, c011 = ux*wy*wz;
        const float c100 = wx*uy*uz, c101 = wx*uy*wz, c110 = wx*wy*uz, c111 = wx*wy*wz;
        float f0 = e000.x*c000, f1 = e000.y*c000;
        f0 = fmaf(e001.x,c001,f0); f1 = fmaf(e001.y,c001,f1);
        f0 = fmaf(e010.x,c010,f0); f1 = fmaf(e010.y,c010,f1);
        f0 = fmaf(e011.x,c011,f0); f1 = fmaf(e011.y,c011,f1);
        f0 = fmaf(e100.x,c100,f0); f1 = fmaf(e100.y,c100,f1);
        f0 = fmaf(e101.x,c101,f0); f1 = fmaf(e101.y,c101,f1);
        f0 = fmaf(e110.x,c110,f0); f1 = fmaf(e110.y,c110,f1);
        f0 = fmaf(e111.x,c111,f0); f1 = fmaf(e111.y,c111,f1);
        const float* w0 = Wd1 + (size_t)(2 * l) * 64;
#pragma unroll
        for (int j = 0; j < 64; ++j)
            y[j] = fmaf(f0, w0[j], fmaf(f1, w0[64 + j], y[j]));
    }
    float d[16];
#pragma unroll
    for (int k = 0; k < 16; ++k) d[k] = bd2[k];
#pragma unroll
    for (int j = 0; j < 64; ++j) {
        const float a = fmaxf(y[j], 0.f);
#pragma unroll
        for (int k = 0; k < 16; ++k) d[k] = fmaf(a, Wd2[j * 16 + k], d[k]);
    }
    out[3 * n + idx] = fmaxf(d[15], 0.f);
    const float dx = dirp[3*idx], dy = dirp[3*idx+1], dz = dirp[3*idx+2];
    float sh[25];
    SH_BLOCK(sh, dx, dy, dz)
    float h1[64];
#pragma unroll
    for (int j = 0; j < 64; ++j) h1[j] = bc1[j];
#pragma unroll
    for (int i = 0; i < 16; ++i) {
#pragma unroll
        for (int j = 0; j < 64; ++j) h1[j] = fmaf(d[i], Wc1[i * 64 + j], h1[j]);
    }
#pragma unroll
    for (int s = 0; s < 25; ++s) {
#pragma unroll
        for (int j = 0; j < 64; ++j) h1[j] = fmaf(sh[s], Wc1[(16 + s) * 64 + j], h1[j]);
    }
    float h2[64];
#pragma unroll
    for (int j = 0; j < 64; ++j) h2[j] = bc2[j];
#pragma unroll
    for (int i = 0; i < 64; ++i) {
        const float a = fmaxf(h1[i], 0.f);
#pragma unroll
        for (int j = 0; j < 64; ++j) h2[j] = fmaf(a, Wc2[i * 64 + j], h2[j]);
    }
    float r0 = bc3[0], r1 = bc3[1], r2 = bc3[2];
#pragma unroll
    for (int j = 0; j < 64; ++j) {
        const float a = fmaxf(h2[j], 0.f);
        r0 = fmaf(a, Wc3[j * 3 + 0], r0);
        r1 = fmaf(a, Wc3[j * 3 + 1], r1);
        r2 = fmaf(a, Wc3[j * 3 + 2], r2);
    }
    out[3 * idx + 0] = 1.f / (1.f + expf(-r0));
    out[3 * idx + 1] = 1.f / (1.f + expf(-r1));
    out[3 * idx + 2] = 1.f / (1.f + expf(-r2));
}

extern "C" void kernel_launch(void* const* d_in, const int* in_sizes, int n_in,
                              void* d_out, int out_size, void* d_ws, size_t ws_size,
                              hipStream_t stream) {
    const float* pos    = (const float*)d_in[0];
    const float* dir    = (const float*)d_in[1];
    const float* tables = (const float*)d_in[2];
    const float* Wd1 = (const float*)d_in[3];
    const float* bd1 = (const float*)d_in[4];
    const float* Wd2 = (const float*)d_in[5];
    const float* bd2 = (const float*)d_in[6];
    const float* Wc1 = (const float*)d_in[7];
    const float* bc1 = (const float*)d_in[8];
    const float* Wc2 = (const float*)d_in[9];
    const float* bc2 = (const float*)d_in[10];
    const float* Wc3 = (const float*)d_in[11];
    const float* bc3 = (const float*)d_in[12];

    const int n = in_sizes[0] / 3;
    const int blocks = (n + 255) / 256;
    const size_t need = (size_t)n * 128;   // 32 floats per point

    if (ws_size >= need) {
        const int blocks4 = (4 * n + 255) / 256;
        ngp_encode4<<<blocks4, 256, 0, stream>>>(pos, tables, (float4*)d_ws, n);
        ngp_mlp_f32<<<blocks, 256, 0, stream>>>((const float4*)d_ws, dir,
                                                Wd1, bd1, Wd2, bd2,
                                                Wc1, bc1, Wc2, bc2, Wc3, bc3,
                                                (float*)d_out, n);
    } else {
        nerf_fused<<<blocks, 256, 0, stream>>>(pos, dir, tables,
                                               Wd1, bd1, Wd2, bd2,
                                               Wc1, bc1, Wc2, bc2, Wc3, bc3,
                                               (float*)d_out, n);
    }
}

// Round 6
// 570.416 us; speedup vs baseline: 1.4614x; 1.4614x over previous
//
#include <hip/hip_runtime.h>
#include <math.h>

#define LEVELS 16
#define TBL 524288          // 2^19 entries per level
#define TMASK (TBL - 1)

// SH degree-4 block, constants computed exactly as round-1 (verified correct).
#define SH_BLOCK(sh, dx, dy, dz)                                                          \
    const float x2 = dx * dx, y2 = dy * dy, z2 = dz * dz;                                 \
    const float xy = dx * dy, xz = dx * dz, yz = dy * dz;                                 \
    const float x4 = x2 * x2, y4 = y2 * y2;                                               \
    const float c0  = (float)(0.5 * sqrt(1.0 / M_PI));                                    \
    const float c1  = (float)(0.5 * sqrt(3.0 / M_PI));                                    \
    const float sub = (float)(0.25 * sqrt(5.0 / M_PI));                                   \
    const float v1  = (float)(0.25 * sqrt(15.0 / M_PI));                                  \
    const float v2  = (float)(0.5 * sqrt(15.0 / M_PI));                                   \
    const float v3  = (float)(0.75 * sqrt(5.0 / M_PI));                                   \
    const float w1c = (float)(0.25 * sqrt(105.0 / M_PI));                                 \
    const float w2c = (float)(0.5 * sqrt(105.0 / M_PI));                                  \
    const float w3c = (float)(0.25 * sqrt(35.0 / (2.0 * M_PI)));                          \
    const float w4c = (float)(0.5 * sqrt(7.0 / (6.0 * M_PI)));                            \
    sh[0] = c0;                                                                           \
    sh[1] = -c1 * dy;                                                                     \
    sh[2] =  c1 * dz;                                                                     \
    sh[3] = -c1 * dx;                                                                     \
    sh[4] =  v2 * xy;                                                                     \
    sh[5] = -v2 * yz;                                                                     \
    sh[6] =  v3 * z2 - sub;                                                               \
    sh[7] = -v2 * xz;                                                                     \
    sh[8] =  v1 * x2 - v1 * y2;                                                           \
    sh[9]  = -w3c * dy * (3.0f * x2 - y2);                                                \
    sh[10] =  w2c * xy * dz;                                                              \
    sh[11] =  w4c * dy * (1.5f - 7.5f * z2);                                              \
    sh[12] =  1.24392110863372f * dz * (1.5f * z2 - 0.5f) - 0.497568443453487f * dz;      \
    sh[13] =  w4c * dx * (1.5f - 7.5f * z2);                                              \
    sh[14] =  w1c * dz * (x2 - y2);                                                       \
    sh[15] = -w3c * dx * (x2 - 3.0f * y2);                                                \
    sh[16] =  2.5033429417967f * xy * (x2 - y2);                                          \
    sh[17] = -1.77013076977993f * yz * (3.0f * x2 - y2);                                  \
    sh[18] =  0.126156626101008f * xy * (52.5f * z2 - 7.5f);                              \
    sh[19] =  0.267618617422916f * dy * (2.33333333333333f * dz * (1.5f - 7.5f * z2) + 4.0f * dz); \
    sh[20] =  1.48099765681286f * dz * (1.66666666666667f * dz * (1.5f * z2 - 0.5f) - 0.666666666666667f * dz) \
              - 0.952069922236839f * z2 + 0.317356640745613f;                             \
    sh[21] =  0.267618617422916f * dx * (2.33333333333333f * dz * (1.5f - 7.5f * z2) + 4.0f * dz); \
    sh[22] =  0.063078313050504f * (x2 - y2) * (52.5f * z2 - 7.5f);                       \
    sh[23] = -1.77013076977993f * xz * (x2 - 3.0f * y2);                                  \
    sh[24] = -3.75501441269506f * x2 * y2 + 0.625835735449176f * x4 + 0.625835735449176f * y4;

// ------------------------------------------------------------------
// Kernel 1: hash-grid gather with level<->XCD affinity.
// Grid = 16 * (n/256) blocks. Block b (round-robin b%8 -> XCD):
//   p = b & 7 (XCD), h = b >> 14 (half), level = 2p + h,
//   chunk c = (b & 16383) >> 3, idx = c*256 + tid.
// Each XCD's L2 holds exactly one 4 MB level table at a time.
// Output: float2 plane per level: ws2[level * n + idx].
// ------------------------------------------------------------------
__global__ __launch_bounds__(256)
void ngp_encode_lvl(const float* __restrict__ pos,
                    const float* __restrict__ tables,
                    float2* __restrict__ ws2, int n)
{
    const int b = blockIdx.x;
    const int p = b & 7;
    const int h = b >> 14;                 // 16384 blocks per half (n = 2^19)
    const int l = 2 * p + h;
    const int c = (b & 16383) >> 3;
    const int idx = c * 256 + threadIdx.x;
    if (idx >= n || l >= LEVELS) return;

    const float px = pos[3 * idx + 0];
    const float py = pos[3 * idx + 1];
    const float pz = pos[3 * idx + 2];

    const float resf = (float)(16 << l);          // exact powers of two
    const float tx = px * resf, ty = py * resf, tz = pz * resf;
    const float fx = floorf(tx), fy = floorf(ty), fz = floorf(tz);
    const float wx = tx - fx, wy = ty - fy, wz = tz - fz;
    const unsigned ix = (unsigned)(int)fx;
    const unsigned iy = (unsigned)(int)fy;
    const unsigned iz = (unsigned)(int)fz;
    const unsigned hy0 = iy * 2654435761u, hy1 = hy0 + 2654435761u;
    const unsigned hz0 = iz * 805459861u,  hz1 = hz0 + 805459861u;
    const unsigned ix1 = ix + 1u;

    const float2* tb = (const float2*)tables + (size_t)l * TBL;
    const float2 e000 = tb[(ix  ^ hy0 ^ hz0) & TMASK];
    const float2 e001 = tb[(ix  ^ hy0 ^ hz1) & TMASK];
    const float2 e010 = tb[(ix  ^ hy1 ^ hz0) & TMASK];
    const float2 e011 = tb[(ix  ^ hy1 ^ hz1) & TMASK];
    const float2 e100 = tb[(ix1 ^ hy0 ^ hz0) & TMASK];
    const float2 e101 = tb[(ix1 ^ hy0 ^ hz1) & TMASK];
    const float2 e110 = tb[(ix1 ^ hy1 ^ hz0) & TMASK];
    const float2 e111 = tb[(ix1 ^ hy1 ^ hz1) & TMASK];

    const float ux = 1.f - wx, uy = 1.f - wy, uz = 1.f - wz;
    const float c000 = ux * uy * uz, c001 = ux * uy * wz;
    const float c010 = ux * wy * uz, c011 = ux * wy * wz;
    const float c100 = wx * uy * uz, c101 = wx * uy * wz;
    const float c110 = wx * wy * uz, c111 = wx * wy * wz;

    float f0 = e000.x * c000, f1 = e000.y * c000;
    f0 = fmaf(e001.x, c001, f0); f1 = fmaf(e001.y, c001, f1);
    f0 = fmaf(e010.x, c010, f0); f1 = fmaf(e010.y, c010, f1);
    f0 = fmaf(e011.x, c011, f0); f1 = fmaf(e011.y, c011, f1);
    f0 = fmaf(e100.x, c100, f0); f1 = fmaf(e100.y, c100, f1);
    f0 = fmaf(e101.x, c101, f0); f1 = fmaf(e101.y, c101, f1);
    f0 = fmaf(e110.x, c110, f0); f1 = fmaf(e110.y, c110, f1);
    f0 = fmaf(e111.x, c111, f0); f1 = fmaf(e111.y, c111, f1);

    ws2[(size_t)l * n + idx] = make_float2(f0, f1);
}

// ------------------------------------------------------------------
// Kernel 2: SH encode + full MLP, per-thread fp32.
// Register-lean restructure: sigma stored early, c1 d-part before SH,
// c2+c3 fused with h2 in 16-chunks (h2[64] never live).
// ------------------------------------------------------------------
__global__ __launch_bounds__(256, 4)
void ngp_mlp_v2(const float2* __restrict__ ws2,
                const float* __restrict__ dirp,
                const float* __restrict__ Wd1, const float* __restrict__ bd1,
                const float* __restrict__ Wd2, const float* __restrict__ bd2,
                const float* __restrict__ Wc1, const float* __restrict__ bc1,
                const float* __restrict__ Wc2, const float* __restrict__ bc2,
                const float* __restrict__ Wc3, const float* __restrict__ bc3,
                float* __restrict__ out, int n)
{
    const int idx = blockIdx.x * blockDim.x + threadIdx.x;
    if (idx >= n) return;

    // ---- d1: y[64] = enc[32] @ Wd1 + bd1 (enc streamed per level) ----
    float y[64];
#pragma unroll
    for (int j = 0; j < 64; ++j) y[j] = bd1[j];
#pragma unroll
    for (int l = 0; l < 16; ++l) {
        const float2 q = ws2[(size_t)l * n + idx];
        const float a0 = q.x;
        const float a1 = q.y;
        const float* w0 = Wd1 + (size_t)(2 * l) * 64;
#pragma unroll
        for (int j = 0; j < 64; ++j)
            y[j] = fmaf(a0, w0[j], fmaf(a1, w0[64 + j], y[j]));
    }

    // ---- d2: d[16] = relu(y) @ Wd2 + bd2 ----
    float d[16];
#pragma unroll
    for (int k = 0; k < 16; ++k) d[k] = bd2[k];
#pragma unroll
    for (int j = 0; j < 64; ++j) {
        const float a = fmaxf(y[j], 0.f);
#pragma unroll
        for (int k = 0; k < 16; ++k) d[k] = fmaf(a, Wd2[j * 16 + k], d[k]);
    }
    out[3 * n + idx] = fmaxf(d[15], 0.f);      // sigma, stored early

    // ---- c1 d-part first (d dies before SH is built) ----
    float h1[64];
#pragma unroll
    for (int j = 0; j < 64; ++j) h1[j] = bc1[j];
#pragma unroll
    for (int i = 0; i < 16; ++i) {
#pragma unroll
        for (int j = 0; j < 64; ++j) h1[j] = fmaf(d[i], Wc1[i * 64 + j], h1[j]);
    }

    // ---- SH degree-4 ----
    const float dx = dirp[3 * idx + 0];
    const float dy = dirp[3 * idx + 1];
    const float dz = dirp[3 * idx + 2];
    float sh[25];
    SH_BLOCK(sh, dx, dy, dz)

    // ---- c1 sh-part ----
#pragma unroll
    for (int s = 0; s < 25; ++s) {
#pragma unroll
        for (int j = 0; j < 64; ++j) h1[j] = fmaf(sh[s], Wc1[(16 + s) * 64 + j], h1[j]);
    }

    // ---- c2 + c3 fused: h2 in 16-chunks, consumed directly into r ----
    float r0 = bc3[0], r1 = bc3[1], r2 = bc3[2];
#pragma unroll
    for (int cch = 0; cch < 4; ++cch) {
        float h2c[16];
#pragma unroll
        for (int k = 0; k < 16; ++k) h2c[k] = bc2[cch * 16 + k];
#pragma unroll
        for (int i = 0; i < 64; ++i) {
            const float a = fmaxf(h1[i], 0.f);
#pragma unroll
            for (int k = 0; k < 16; ++k)
                h2c[k] = fmaf(a, Wc2[i * 64 + cch * 16 + k], h2c[k]);
        }
#pragma unroll
        for (int k = 0; k < 16; ++k) {
            const float a2 = fmaxf(h2c[k], 0.f);
            const int row = cch * 16 + k;
            r0 = fmaf(a2, Wc3[row * 3 + 0], r0);
            r1 = fmaf(a2, Wc3[row * 3 + 1], r1);
            r2 = fmaf(a2, Wc3[row * 3 + 2], r2);
        }
    }
    out[3 * idx + 0] = 1.f / (1.f + expf(-r0));
    out[3 * idx + 1] = 1.f / (1.f + expf(-r1));
    out[3 * idx + 2] = 1.f / (1.f + expf(-r2));
}

// ------------------------------------------------------------------
// Fallback: round-1 fused kernel (if ws too small / n not 2^19) — proven
// ------------------------------------------------------------------
__global__ __launch_bounds__(256)
void nerf_fused(const float* __restrict__ pos,
                const float* __restrict__ dirp,
                const float* __restrict__ tables,
                const float* __restrict__ Wd1, const float* __restrict__ bd1,
                const float* __restrict__ Wd2, const float* __restrict__ bd2,
                const float* __restrict__ Wc1, const float* __restrict__ bc1,
                const float* __restrict__ Wc2, const float* __restrict__ bc2,
                const float* __restrict__ Wc3, const float* __restrict__ bc3,
                float* __restrict__ out, int n)
{
    const int idx = blockIdx.x * blockDim.x + threadIdx.x;
    if (idx >= n) return;
    const float px = pos[3 * idx + 0], py = pos[3 * idx + 1], pz = pos[3 * idx + 2];
    float y[64];
#pragma unroll
    for (int j = 0; j < 64; ++j) y[j] = bd1[j];
#pragma unroll
    for (int l = 0; l < LEVELS; ++l) {
        const float resf = (float)(16 << l);
        const float tx = px * resf, ty = py * resf, tz = pz * resf;
        const float fx = floorf(tx), fy = floorf(ty), fz = floorf(tz);
        const float wx = tx - fx, wy = ty - fy, wz = tz - fz;
        const unsigned ix = (unsigned)(int)fx, iy = (unsigned)(int)fy, iz = (unsigned)(int)fz;
        const unsigned hy0 = iy * 2654435761u, hy1 = hy0 + 2654435761u;
        const unsigned hz0 = iz * 805459861u,  hz1 = hz0 + 805459861u;
        const unsigned ix1 = ix + 1u;
        const float2* tb = (const float2*)tables + (size_t)l * TBL;
        const float2 e000 = tb[(ix  ^ hy0 ^ hz0) & TMASK];
        const float2 e001 = tb[(ix  ^ hy0 ^ hz1) & TMASK];
        const float2 e010 = tb[(ix  ^ hy1 ^ hz0) & TMASK];
        const float2 e011 = tb[(ix  ^ hy1 ^ hz1) & TMASK];
        const float2 e100 = tb[(ix1 ^ hy0 ^ hz0) & TMASK];
        const float2 e101 = tb[(ix1 ^ hy0 ^ hz1) & TMASK];
        const float2 e110 = tb[(ix1 ^ hy1 ^ hz0) & TMASK];
        const float2 e111 = tb[(ix1 ^ hy1 ^ hz1) & TMASK];
        const float ux = 1.f - wx, uy = 1.f - wy, uz = 1.f - wz;
        const float c000 = ux*uy*uz, c001 = ux*uy*wz, c010 = ux*wy*uz, c011 = ux*wy*wz;
        const float c100 = wx*uy*uz, c101 = wx*uy*wz, c110 = wx*wy*uz, c111 = wx*wy*wz;
        float f0 = e000.x*c000, f1 = e000.y*c000;
        f0 = fmaf(e001.x,c001,f0); f1 = fmaf(e001.y,c001,f1);
        f0 = fmaf(e010.x,c010,f0); f1 = fmaf(e010.y,c010,f1);
        f0 = fmaf(e011.x,c011,f0); f1 = fmaf(e011.y,c011,f1);
        f0 = fmaf(e100.x,c100,f0); f1 = fmaf(e100.y,c100,f1);
        f0 = fmaf(e101.x,c101,f0); f1 = fmaf(e101.y,c101,f1);
        f0 = fmaf(e110.x,c110,f0); f1 = fmaf(e110.y,c110,f1);
        f0 = fmaf(e111.x,c111,f0); f1 = fmaf(e111.y,c111,f1);
        const float* w0 = Wd1 + (size_t)(2 * l) * 64;
#pragma unroll
        for (int j = 0; j < 64; ++j)
            y[j] = fmaf(f0, w0[j], fmaf(f1, w0[64 + j], y[j]));
    }
    float d[16];
#pragma unroll
    for (int k = 0; k < 16; ++k) d[k] = bd2[k];
#pragma unroll
    for (int j = 0; j < 64; ++j) {
        const float a = fmaxf(y[j], 0.f);
#pragma unroll
        for (int k = 0; k < 16; ++k) d[k] = fmaf(a, Wd2[j * 16 + k], d[k]);
    }
    out[3 * n + idx] = fmaxf(d[15], 0.f);
    const float dx = dirp[3*idx], dy = dirp[3*idx+1], dz = dirp[3*idx+2];
    float sh[25];
    SH_BLOCK(sh, dx, dy, dz)
    float h1[64];
#pragma unroll
    for (int j = 0; j < 64; ++j) h1[j] = bc1[j];
#pragma unroll
    for (int i = 0; i < 16; ++i) {
#pragma unroll
        for (int j = 0; j < 64; ++j) h1[j] = fmaf(d[i], Wc1[i * 64 + j], h1[j]);
    }
#pragma unroll
    for (int s = 0; s < 25; ++s) {
#pragma unroll
        for (int j = 0; j < 64; ++j) h1[j] = fmaf(sh[s], Wc1[(16 + s) * 64 + j], h1[j]);
    }
    float h2[64];
#pragma unroll
    for (int j = 0; j < 64; ++j) h2[j] = bc2[j];
#pragma unroll
    for (int i = 0; i < 64; ++i) {
        const float a = fmaxf(h1[i], 0.f);
#pragma unroll
        for (int j = 0; j < 64; ++j) h2[j] = fmaf(a, Wc2[i * 64 + j], h2[j]);
    }
    float r0 = bc3[0], r1 = bc3[1], r2 = bc3[2];
#pragma unroll
    for (int j = 0; j < 64; ++j) {
        const float a = fmaxf(h2[j], 0.f);
        r0 = fmaf(a, Wc3[j * 3 + 0], r0);
        r1 = fmaf(a, Wc3[j * 3 + 1], r1);
        r2 = fmaf(a, Wc3[j * 3 + 2], r2);
    }
    out[3 * idx + 0] = 1.f / (1.f + expf(-r0));
    out[3 * idx + 1] = 1.f / (1.f + expf(-r1));
    out[3 * idx + 2] = 1.f / (1.f + expf(-r2));
}

extern "C" void kernel_launch(void* const* d_in, const int* in_sizes, int n_in,
                              void* d_out, int out_size, void* d_ws, size_t ws_size,
                              hipStream_t stream) {
    const float* pos    = (const float*)d_in[0];
    const float* dir    = (const float*)d_in[1];
    const float* tables = (const float*)d_in[2];
    const float* Wd1 = (const float*)d_in[3];
    const float* bd1 = (const float*)d_in[4];
    const float* Wd2 = (const float*)d_in[5];
    const float* bd2 = (const float*)d_in[6];
    const float* Wc1 = (const float*)d_in[7];
    const float* bc1 = (const float*)d_in[8];
    const float* Wc2 = (const float*)d_in[9];
    const float* bc2 = (const float*)d_in[10];
    const float* Wc3 = (const float*)d_in[11];
    const float* bc3 = (const float*)d_in[12];

    const int n = in_sizes[0] / 3;
    const int blocks = (n + 255) / 256;
    const size_t need = (size_t)n * 128;   // 16 float2 planes = 32 floats/point

    // level-affinity grid math assumes n == 2^19 (blocks/level = 2048)
    if (ws_size >= need && n == 524288) {
        ngp_encode_lvl<<<16 * blocks, 256, 0, stream>>>(pos, tables, (float2*)d_ws, n);
        ngp_mlp_v2<<<blocks, 256, 0, stream>>>((const float2*)d_ws, dir,
                                               Wd1, bd1, Wd2, bd2,
                                               Wc1, bc1, Wc2, bc2, Wc3, bc3,
                                               (float*)d_out, n);
    } else {
        nerf_fused<<<blocks, 256, 0, stream>>>(pos, dir, tables,
                                               Wd1, bd1, Wd2, bd2,
                                               Wc1, bc1, Wc2, bc2, Wc3, bc3,
                                               (float*)d_out, n);
    }
}